// Round 5
// baseline (418.390 us; speedup 1.0000x reference)
//
#include <hip/hip_runtime.h>
#include <hip/hip_bf16.h>

// ---------------- problem constants ----------------
#define B_N   8
#define S_N   4096
#define D_N   256          // DQK == DV
#define QBLK  128          // q rows per block: 4 waves x 32 rows
#define KVBLK 64           // keys per tile
#define NT    (S_N / KVBLK)
#define SCALE 0.0625f      // 1/sqrt(256), folded into Q prepass

typedef __attribute__((ext_vector_type(8)))  short bf16x8;
typedef __attribute__((ext_vector_type(16))) float f32x16;

// ---------------- async global->LDS (16B/lane, wave-uniform LDS base) -------
__device__ __forceinline__ void async16(const char* g, char* l) {
  __builtin_amdgcn_global_load_lds(
      (const __attribute__((address_space(1))) void*)g,
      (__attribute__((address_space(3))) void*)l, 16, 0, 0);
}

__device__ __forceinline__ unsigned cvt_pk_bf16(float lo, float hi) {
  unsigned r;
  asm("v_cvt_pk_bf16_f32 %0, %1, %2" : "=v"(r) : "v"(lo), "v"(hi));
  return r;
}
// upper 32 lanes of a <-> lower 32 lanes of b
__device__ __forceinline__ void swap32(unsigned& a, unsigned& b) {
  asm("v_permlane32_swap_b32 %0, %1" : "+v"(a), "+v"(b));
}
// full-wave combine of per-half partials (opaque asm keeps a,b distinct regs)
__device__ __forceinline__ float xhalf_max(float x) {
  float a = x, b = x;
  asm("" : "+v"(b));
  asm("v_permlane32_swap_b32 %0, %1" : "+v"(a), "+v"(b));
  return fmaxf(a, b);
}
__device__ __forceinline__ float xhalf_add(float x) {
  float a = x, b = x;
  asm("" : "+v"(b));
  asm("v_permlane32_swap_b32 %0, %1" : "+v"(a), "+v"(b));
  return a + b;
}

// ---------------- prepass: NCHW -> (B,S,D) bf16 with pos add (+scale) -------
__global__ void prep_qk(const float* __restrict__ src, const float* __restrict__ pos,
                        __hip_bfloat16* __restrict__ dst, float mul) {
  __shared__ float tile[64][65];
  const int b  = blockIdx.z;
  const int s0 = blockIdx.x * 64;
  const int c0 = blockIdx.y * 64;
  const int t  = threadIdx.x;
  const int x  = t & 63;
  const int y4 = t >> 6;
  const float* sp = src + ((size_t)b * D_N + c0) * S_N + s0;
#pragma unroll
  for (int i = 0; i < 16; ++i) {
    int c = y4 + i * 4;
    tile[c][x] = sp[(size_t)c * S_N + x];
  }
  __syncthreads();
  __hip_bfloat16* dp = dst + ((size_t)b * S_N + s0) * D_N + c0;
  const float* pp = pos + (size_t)s0 * D_N + c0;
#pragma unroll
  for (int i = 0; i < 16; ++i) {
    int s = y4 + i * 4;
    float v = (tile[x][s] + pp[(size_t)s * D_N + x]) * mul;
    dp[(size_t)s * D_N + x] = __float2bfloat16(v);
  }
}

// V: (B,D,S) fp32 -> (B,D,S) bf16 cast
struct alignas(8) bf4 { __hip_bfloat16 a, b, c, d; };
__global__ void prep_v(const float* __restrict__ src, __hip_bfloat16* __restrict__ dst) {
  size_t i = (size_t)blockIdx.x * blockDim.x + threadIdx.x;
  float4 v = reinterpret_cast<const float4*>(src)[i];
  bf4 o { __float2bfloat16(v.x), __float2bfloat16(v.y),
          __float2bfloat16(v.z), __float2bfloat16(v.w) };
  *reinterpret_cast<bf4*>(dst + i * 4) = o;
}

// ---------------- flash attention: QBLK=128, double-buffered KV -------------
// LDS (131072 B): buf0 [0,64K): K 64x512B swz | V 256x128B swz
//                 buf1 [64K,128K): same
#define LDS_BYTES 131072

__global__ __launch_bounds__(256, 1) void attn_kernel(
    const __hip_bfloat16* __restrict__ Qb, const __hip_bfloat16* __restrict__ Kb,
    const __hip_bfloat16* __restrict__ Vtb, float* __restrict__ out) {
  __shared__ __align__(16) char lds[LDS_BYTES];

  const int tid  = threadIdx.x;
  const int wave = tid >> 6;
  const int lane = tid & 63;
  const int l31  = lane & 31;
  const int h    = lane >> 5;
  const int l7   = lane & 7;

  // XCD swizzle: hw block i -> XCD i%8; all of batch b on XCD b
  const int lin   = blockIdx.x;          // 0..255
  const int b     = lin & 7;
  const int qtile = lin >> 3;            // 0..31
  const int q0    = qtile * QBLK + wave * 32;

  // ---- Q fragments resident in registers (B-operand layout) ----
  bf16x8 qf[16];
  {
    const __hip_bfloat16* qp = Qb + ((size_t)b * S_N + q0 + l31) * D_N + h * 8;
#pragma unroll
    for (int kc = 0; kc < 16; ++kc)
      qf[kc] = *reinterpret_cast<const bf16x8*>(qp + kc * 16);
  }

  // ---- accumulators ----
  f32x16 o[8];
#pragma unroll
  for (int df = 0; df < 8; ++df)
#pragma unroll
    for (int r = 0; r < 16; ++r) o[df][r] = 0.f;
  float m_ = -1e30f, l_ = 0.f;

  const char* kgbase = reinterpret_cast<const char*>(Kb  + (size_t)b * S_N * D_N);
  const char* vgbase = reinterpret_cast<const char*>(Vtb + (size_t)b * D_N * S_N);

  // stage tile t into buffer buf: 64 x 1KB segments; waves 0-1 K, waves 2-3 V
  auto STAGE = [&](int buf, int t) {
    char* base = lds + buf * 65536;
    if (wave < 2) {
      const char* kt = kgbase + (size_t)t * KVBLK * (D_N * 2);
#pragma unroll
      for (int i = 0; i < 16; ++i) {
        int c    = wave * 16 + i;
        int T    = c * 1024 + lane * 16;
        int row  = T >> 9;
        int colb = T & 511;
        async16(kt + row * 512 + (colb ^ ((row & 7) << 4)), base + c * 1024);
      }
    } else {
      const char* vt = vgbase + (size_t)t * KVBLK * 2;
#pragma unroll
      for (int i = 0; i < 16; ++i) {
        int c    = (wave - 2) * 16 + i;
        int T    = c * 1024 + lane * 16;
        int d    = T >> 7;
        int colb = T & 127;
        async16(vt + (size_t)d * (S_N * 2) + (colb ^ ((d & 7) << 4)),
                base + 32768 + c * 1024);
      }
    }
  };

  STAGE(0, 0);                           // prologue

  for (int t = 0; t < NT; ++t) {
    const int cur = t & 1;
    if (t + 1 < NT) {
      STAGE(cur ^ 1, t + 1);             // issue next tile's loads (stay in flight)
      asm volatile("s_waitcnt vmcnt(16)" ::: "memory");   // tile t landed (per wave)
    } else {
      asm volatile("s_waitcnt vmcnt(0)" ::: "memory");
    }
    __builtin_amdgcn_s_barrier();        // tile t visible to all waves

    const char* Klds = lds + cur * 65536;
    const char* Vlds = Klds + 32768;

    // ---- QK^T (swapped): S^T[key][q] = mfma(A=K, B=Q) ----
    f32x16 se[2];
#pragma unroll
    for (int e = 0; e < 2; ++e) {
#pragma unroll
      for (int r = 0; r < 16; ++r) se[e][r] = 0.f;
      const char* kr = Klds + (e * 32 + l31) * 512;
      const int swz = l7 << 4;           // key&7 == lane&7
#pragma unroll
      for (int kc = 0; kc < 16; ++kc) {
        bf16x8 kf = *reinterpret_cast<const bf16x8*>(kr + ((kc * 32 + h * 16) ^ swz));
        se[e] = __builtin_amdgcn_mfma_f32_32x32x16_bf16(kf, qf[kc], se[e], 0, 0, 0);
      }
    }

    // ---- online softmax (lane-local + one cross-half combine) ----
    float t8[8];
#pragma unroll
    for (int i = 0; i < 8; ++i)
      t8[i] = fmaxf(fmaxf(se[0][i], se[0][i + 8]), fmaxf(se[1][i], se[1][i + 8]));
    float pm = fmaxf(fmaxf(fmaxf(t8[0], t8[1]), fmaxf(t8[2], t8[3])),
                     fmaxf(fmaxf(t8[4], t8[5]), fmaxf(t8[6], t8[7])));
    float pmax = xhalf_max(pm);

    if (!__all(pmax <= m_ + 8.f)) {      // defer-max
      float mn = fmaxf(m_, pmax);
      float al = __expf(m_ - mn);
      m_ = mn;
      l_ *= al;
#pragma unroll
      for (int df = 0; df < 8; ++df)
#pragma unroll
        for (int r = 0; r < 16; ++r) o[df][r] *= al;
    }
#pragma unroll
    for (int r = 0; r < 16; ++r) se[0][r] = __expf(se[0][r] - m_);
#pragma unroll
    for (int r = 0; r < 16; ++r) se[1][r] = __expf(se[1][r] - m_);
    float s8[8];
#pragma unroll
    for (int i = 0; i < 8; ++i)
      s8[i] = (se[0][i] + se[0][i + 8]) + (se[1][i] + se[1][i + 8]);
    float rs = ((s8[0] + s8[1]) + (s8[2] + s8[3])) + ((s8[4] + s8[5]) + (s8[6] + s8[7]));
    l_ += xhalf_add(rs);

    // ---- P -> bf16 B-fragments in-register (cvt_pk + permlane32_swap) ----
    union U8 { unsigned u[4]; bf16x8 v; };
    U8 pb[4];
#pragma unroll
    for (int e = 0; e < 2; ++e) {
      unsigned u0 = cvt_pk_bf16(se[e][0],  se[e][1]);
      unsigned v0 = cvt_pk_bf16(se[e][4],  se[e][5]);
      swap32(u0, v0);
      unsigned u1 = cvt_pk_bf16(se[e][2],  se[e][3]);
      unsigned v1 = cvt_pk_bf16(se[e][6],  se[e][7]);
      swap32(u1, v1);
      pb[2 * e].u[0] = u0; pb[2 * e].u[1] = u1;
      pb[2 * e].u[2] = v0; pb[2 * e].u[3] = v1;
      unsigned u2 = cvt_pk_bf16(se[e][8],  se[e][9]);
      unsigned v2 = cvt_pk_bf16(se[e][12], se[e][13]);
      swap32(u2, v2);
      unsigned u3 = cvt_pk_bf16(se[e][10], se[e][11]);
      unsigned v3 = cvt_pk_bf16(se[e][14], se[e][15]);
      swap32(u3, v3);
      pb[2 * e + 1].u[0] = u2; pb[2 * e + 1].u[1] = u3;
      pb[2 * e + 1].u[2] = v2; pb[2 * e + 1].u[3] = v3;
    }

    // ---- PV (swapped): O^T[d][q] += mfma(A=V^T, B=P) ----
#pragma unroll
    for (int df = 0; df < 8; ++df) {
      const char* vr = Vlds + (df * 32 + l31) * 128;
      const int swz = l7 << 4;           // d&7 == lane&7
#pragma unroll
      for (int kf = 0; kf < 4; ++kf) {
        bf16x8 vf = *reinterpret_cast<const bf16x8*>(vr + ((kf * 32 + h * 16) ^ swz));
        o[df] = __builtin_amdgcn_mfma_f32_32x32x16_bf16(vf, pb[kf].v, o[df], 0, 0, 0);
      }
    }

    __builtin_amdgcn_s_barrier();        // tile t fully consumed; buf reusable
  }

  // ---- epilogue: normalize and store O^T directly to (B,D,S) fp32 ----
  const float invl = 1.0f / l_;
  float* ob = out + (size_t)b * D_N * S_N + q0 + l31;
#pragma unroll
  for (int df = 0; df < 8; ++df)
#pragma unroll
    for (int r = 0; r < 16; ++r) {
      int d = df * 32 + (r & 3) + 8 * (r >> 2) + 4 * h;
      ob[(size_t)d * S_N] = o[df][r] * invl;
    }
}

// ---------------- launch ----------------
extern "C" void kernel_launch(void* const* d_in, const int* in_sizes, int n_in,
                              void* d_out, int out_size, void* d_ws, size_t ws_size,
                              hipStream_t stream) {
  const float* queries = (const float*)d_in[0];
  const float* keys    = (const float*)d_in[1];
  const float* values  = (const float*)d_in[2];
  const float* q_pos   = (const float*)d_in[3];
  const float* k_pos   = (const float*)d_in[4];
  float* out = (float*)d_out;

  const size_t per = (size_t)B_N * S_N * D_N;
  __hip_bfloat16* Qb  = (__hip_bfloat16*)d_ws;
  __hip_bfloat16* Kb  = Qb + per;
  __hip_bfloat16* Vtb = Kb + per;          // 50.3 MB of ws total

  prep_qk<<<dim3(S_N / 64, D_N / 64, B_N), 256, 0, stream>>>(queries, q_pos, Qb, SCALE);
  prep_qk<<<dim3(S_N / 64, D_N / 64, B_N), 256, 0, stream>>>(keys,    k_pos, Kb, 1.0f);
  prep_v <<<dim3((unsigned)(per / 4 / 256)), 256, 0, stream>>>(values, Vtb);
  attn_kernel<<<dim3((S_N / QBLK) * B_N), 256, 0, stream>>>(Qb, Kb, Vtb, out);
}

// Round 6
// 285.695 us; speedup vs baseline: 1.4645x; 1.4645x over previous
//
#include <hip/hip_runtime.h>
#include <hip/hip_bf16.h>

// ---------------- problem constants ----------------
#define B_N   8
#define S_N   4096
#define D_N   256          // DQK == DV
#define QBLK  32           // q rows per block: 2 waves x 16 rows
#define KVBLK 32           // keys per tile
#define NT    (S_N / KVBLK)
#define SCALE 0.0625f      // 1/sqrt(256), folded into Q prepass

typedef __attribute__((ext_vector_type(8))) short bf16x8;
typedef __attribute__((ext_vector_type(4))) float f32x4;

// ---------------- async global->LDS (16B/lane, wave-uniform LDS base) -------
__device__ __forceinline__ void async16(const char* g, char* l) {
  __builtin_amdgcn_global_load_lds(
      (const __attribute__((address_space(1))) void*)g,
      (__attribute__((address_space(3))) void*)l, 16, 0, 0);
}

__device__ __forceinline__ unsigned cvt_pk_bf16(float lo, float hi) {
  unsigned r;
  asm("v_cvt_pk_bf16_f32 %0, %1, %2" : "=v"(r) : "v"(lo), "v"(hi));
  return r;
}

// ---------------- prepass: NCHW -> (B,S,D) bf16 with pos add (+scale) -------
__global__ void prep_qk(const float* __restrict__ src, const float* __restrict__ pos,
                        __hip_bfloat16* __restrict__ dst, float mul) {
  __shared__ float tile[64][65];
  const int b  = blockIdx.z;
  const int s0 = blockIdx.x * 64;
  const int c0 = blockIdx.y * 64;
  const int t  = threadIdx.x;
  const int x  = t & 63;
  const int y4 = t >> 6;
  const float* sp = src + ((size_t)b * D_N + c0) * S_N + s0;
#pragma unroll
  for (int i = 0; i < 16; ++i) {
    int c = y4 + i * 4;
    tile[c][x] = sp[(size_t)c * S_N + x];
  }
  __syncthreads();
  __hip_bfloat16* dp = dst + ((size_t)b * S_N + s0) * D_N + c0;
  const float* pp = pos + (size_t)s0 * D_N + c0;
#pragma unroll
  for (int i = 0; i < 16; ++i) {
    int s = y4 + i * 4;
    float v = (tile[x][s] + pp[(size_t)s * D_N + x]) * mul;
    dp[(size_t)s * D_N + x] = __float2bfloat16(v);
  }
}

// V: (B,D,S) fp32 -> (B,D,S) bf16 cast
struct alignas(8) bf4 { __hip_bfloat16 a, b, c, d; };
__global__ void prep_v(const float* __restrict__ src, __hip_bfloat16* __restrict__ dst) {
  size_t i = (size_t)blockIdx.x * blockDim.x + threadIdx.x;
  float4 v = reinterpret_cast<const float4*>(src)[i];
  bf4 o { __float2bfloat16(v.x), __float2bfloat16(v.y),
          __float2bfloat16(v.z), __float2bfloat16(v.w) };
  *reinterpret_cast<bf4*>(dst + i * 4) = o;
}

// ---------------- flash attention: small blocks, 4 independent per CU -------
// LDS (32768 B):
//   [0,16K)  K tile: 32 rows x 512B. Row r holds global key key0 + pi(r),
//            pi(r) = 8*((r>>2)&3) + (r&3) + 4*(r>>4)  (makes QK C-frag key
//            distribution == PV B-operand k-layout -> zero-shuffle P repack).
//            16B slots XOR-swizzled: phys_slot = logical_slot ^ (r&7).
//   [16K,32K) V tile: 256 d-rows x 64B (32 keys, natural order); 16B chunk
//            swizzle: phys = logical ^ ((d>>1)&3).  Both reads bank-verified
//            2-way (free).
#define LDS_BYTES 32768

__global__ __launch_bounds__(128, 2) void attn_kernel(
    const __hip_bfloat16* __restrict__ Qb, const __hip_bfloat16* __restrict__ Kb,
    const __hip_bfloat16* __restrict__ Vtb, float* __restrict__ out) {
  __shared__ __align__(16) char lds[LDS_BYTES];

  const int tid  = threadIdx.x;
  const int wave = tid >> 6;
  const int lane = tid & 63;
  const int l15  = lane & 15;        // q within wave tile / d within PV frag
  const int g    = lane >> 4;        // 4-lane-group index (k-grouping)

  // XCD swizzle: hw block i -> XCD i%8; all of batch b on XCD b
  const int lin   = blockIdx.x;          // 0..1023
  const int b     = lin & 7;
  const int qtile = lin >> 3;            // 0..127
  const int q0    = qtile * QBLK + wave * 16;

  // ---- Q fragments resident (B-operand: col=l15=q, k = g*8+j per 32-chunk) --
  bf16x8 qf[8];
  {
    const __hip_bfloat16* qp = Qb + ((size_t)b * S_N + q0 + l15) * D_N + g * 8;
#pragma unroll
    for (int kc = 0; kc < 8; ++kc)
      qf[kc] = *reinterpret_cast<const bf16x8*>(qp + kc * 32);
  }

  // ---- accumulators: O^T 16 d-frags (C: col=q, row=d sub) ----
  f32x4 o[16];
#pragma unroll
  for (int df = 0; df < 16; ++df) o[df] = f32x4{0.f, 0.f, 0.f, 0.f};
  float m_ = -1e30f, l_ = 0.f;

  char* Klds = lds;
  char* Vlds = lds + 16384;
  const char* kgbase = reinterpret_cast<const char*>(Kb  + (size_t)b * S_N * D_N);
  const char* vgbase = reinterpret_cast<const char*>(Vtb + (size_t)b * D_N * S_N);

  for (int t = 0; t < NT; ++t) {
    const int key0 = t * KVBLK;
    __syncthreads();                     // previous tile fully consumed
    if (wave == 0) {
      // K: 16 segs of 1KB (rows 2c,2c+1), permuted rows + slot swizzle
      const char* kt = kgbase + (size_t)key0 * 512;
#pragma unroll
      for (int c = 0; c < 16; ++c) {
        int r    = 2 * c + (lane >> 5);
        int pi   = ((r >> 2) & 3) * 8 + (r & 3) + ((r >> 4) << 2);
        int slot = lane & 31;
        async16(kt + pi * 512 + ((slot ^ (r & 7)) << 4), Klds + c * 1024);
      }
    } else {
      // V: 16 segs of 1KB (16 d-rows each), chunk swizzle
#pragma unroll
      for (int c = 0; c < 16; ++c) {
        int d  = c * 16 + (lane >> 2);
        int lc = (lane & 3) ^ ((d >> 1) & 3);
        async16(vgbase + (size_t)d * (S_N * 2) + key0 * 2 + lc * 16,
                Vlds + c * 1024);
      }
    }
    __syncthreads();                     // staged data visible (vmcnt drained)

    // ---- QK^T (swapped): S^T[key-slot][q] = mfma(A=K, B=Q) ----
    f32x4 se[2];
#pragma unroll
    for (int nf = 0; nf < 2; ++nf) {
      se[nf] = f32x4{0.f, 0.f, 0.f, 0.f};
      const int  row = nf * 16 + l15;
      const char* kr = Klds + row * 512;
      const int  swz = (row & 7) << 4;
#pragma unroll
      for (int kc = 0; kc < 8; ++kc) {
        bf16x8 kf = *reinterpret_cast<const bf16x8*>(kr + ((kc * 64 + g * 16) ^ swz));
        se[nf] = __builtin_amdgcn_mfma_f32_16x16x32_bf16(kf, qf[kc], se[nf], 0, 0, 0);
      }
    }
    // lane(l15=q, g) now holds keys: se[nf][r] = key 8g + 4nf + r  (via pi)

    // ---- online softmax: 8 local + 2 cross-group shuffles ----
    float pm = fmaxf(fmaxf(fmaxf(se[0][0], se[0][1]), fmaxf(se[0][2], se[0][3])),
                     fmaxf(fmaxf(se[1][0], se[1][1]), fmaxf(se[1][2], se[1][3])));
    pm = fmaxf(pm, __shfl_xor(pm, 16));
    pm = fmaxf(pm, __shfl_xor(pm, 32));

    if (!__all(pm <= m_ + 8.f)) {        // defer-max
      float mn = fmaxf(m_, pm);
      float al = __expf(m_ - mn);
      m_ = mn;
      l_ *= al;
#pragma unroll
      for (int df = 0; df < 16; ++df) {
        o[df][0] *= al; o[df][1] *= al; o[df][2] *= al; o[df][3] *= al;
      }
    }
#pragma unroll
    for (int nf = 0; nf < 2; ++nf)
#pragma unroll
      for (int r = 0; r < 4; ++r) se[nf][r] = __expf(se[nf][r] - m_);
    float rs = (se[0][0] + se[0][1]) + (se[0][2] + se[0][3]) +
               (se[1][0] + se[1][1]) + (se[1][2] + se[1][3]);
    rs += __shfl_xor(rs, 16);
    rs += __shfl_xor(rs, 32);
    l_ += rs;

    // ---- P -> PV B-fragment: pure in-lane pack (keys 8g..8g+7 in order) ----
    union { unsigned u[4]; bf16x8 v; } pb;
    pb.u[0] = cvt_pk_bf16(se[0][0], se[0][1]);
    pb.u[1] = cvt_pk_bf16(se[0][2], se[0][3]);
    pb.u[2] = cvt_pk_bf16(se[1][0], se[1][1]);
    pb.u[3] = cvt_pk_bf16(se[1][2], se[1][3]);

    // ---- PV (swapped): O^T[d][q] += mfma(A=V^T, B=P) ----
#pragma unroll
    for (int df = 0; df < 16; ++df) {
      const int d = df * 16 + l15;
      bf16x8 vf = *reinterpret_cast<const bf16x8*>(
          Vlds + d * 64 + ((g ^ ((d >> 1) & 3)) << 4));
      o[df] = __builtin_amdgcn_mfma_f32_16x16x32_bf16(vf, pb.v, o[df], 0, 0, 0);
    }
  }

  // ---- epilogue: normalize, store O^T directly to (B,D,S) fp32 ----
  const float inv = 1.0f / l_;
  float* ob = out + (size_t)b * D_N * S_N + q0 + l15;
#pragma unroll
  for (int df = 0; df < 16; ++df)
#pragma unroll
    for (int r = 0; r < 4; ++r) {
      int d = df * 16 + g * 4 + r;
      ob[(size_t)d * S_N] = o[df][r] * inv;
    }
}

// ---------------- launch ----------------
extern "C" void kernel_launch(void* const* d_in, const int* in_sizes, int n_in,
                              void* d_out, int out_size, void* d_ws, size_t ws_size,
                              hipStream_t stream) {
  const float* queries = (const float*)d_in[0];
  const float* keys    = (const float*)d_in[1];
  const float* values  = (const float*)d_in[2];
  const float* q_pos   = (const float*)d_in[3];
  const float* k_pos   = (const float*)d_in[4];
  float* out = (float*)d_out;

  const size_t per = (size_t)B_N * S_N * D_N;
  __hip_bfloat16* Qb  = (__hip_bfloat16*)d_ws;
  __hip_bfloat16* Kb  = Qb + per;
  __hip_bfloat16* Vtb = Kb + per;          // 50.3 MB of ws total

  prep_qk<<<dim3(S_N / 64, D_N / 64, B_N), 256, 0, stream>>>(queries, q_pos, Qb, SCALE);
  prep_qk<<<dim3(S_N / 64, D_N / 64, B_N), 256, 0, stream>>>(keys,    k_pos, Kb, 1.0f);
  prep_v <<<dim3((unsigned)(per / 4 / 256)), 256, 0, stream>>>(values, Vtb);
  attn_kernel<<<dim3((S_N / QBLK) * B_N), 128, 0, stream>>>(Qb, Kb, Vtb, out);
}